// Round 6
// baseline (516.674 us; speedup 1.0000x reference)
//
#include <hip/hip_runtime.h>
#include <hip/hip_bf16.h>
#include <stdint.h>

// Problem constants (fixed shapes from setup_inputs)
#define BB 4
#define CCH 32
#define HH 128
#define WW 128
#define SCALE 2
#define HO 256
#define WO 256
#define QQ (HO*WO)          // 65536 queries per batch
#define HWH (HH*WW)         // 16384
#define MT 64               // queries per workgroup (16 per wave)
#define KPAD 264            // act row stride (bf16): 256 + 8 pad
#define PSTR 40             // pred/routing row stride (bf16): 32 + 8 pad

// Transposed bf16 weight layout offsets in d_ws (elements), each [N][KP] row-major
#define WOFF_L0 0           // [256][64]   (K=36 zero-padded to 64)
#define WOFF_L1 16384       // [256][256]
#define WOFF_L2 81920       // [32][256]
#define WOFF_R0 90112       // [256][32]
#define WOFF_R1 98304       // [32][256]
#define WOFF_O0 106496      // [256][32]
#define WOFF_O1 114688      // [16][256]  (N=2 zero-padded to 16)
#define WTOT    118784

typedef unsigned short u16;
typedef __attribute__((ext_vector_type(8))) __bf16 bf16x8;
typedef __attribute__((ext_vector_type(4))) float f32x4;

// Intra-wave LDS ordering: HW wait for all DS ops + compiler reorder fence.
// All data flow in this kernel is wave-private (rows [w*16, w*16+16)), so no
// s_barrier is needed anywhere — this replaces R5's 10 __syncthreads.
#define LFENCE() asm volatile("s_waitcnt lgkmcnt(0)" ::: "memory")

__device__ __forceinline__ f32x4 MFMA(bf16x8 a, bf16x8 b, f32x4 c) {
  return __builtin_amdgcn_mfma_f32_16x16x32_bf16(a, b, c, 0, 0, 0);
}

// Software f32->bf16 RNE (cold paths only).
__device__ __forceinline__ u16 f2bf(float f) {
  union { float f; unsigned int u; } v; v.f = f;
  unsigned int u = v.u;
  u += 0x7fffu + ((u >> 16) & 1u);
  return (u16)(u >> 16);
}

// Packed f32x2 -> bf16x2 via hip_bf16 header (HW packed cvt, RNE). R4-proven.
__device__ __forceinline__ uint32_t pkbf(float a, float b) {
  union { __hip_bfloat162 h; uint32_t u; } cv;
  cv.h = __float22bfloat162_rn(make_float2(a, b));
  return cv.u;
}

__device__ __forceinline__ float bf2f(u16 u) {
  union { unsigned int u; float f; } v; v.u = ((unsigned int)u) << 16;
  return v.f;
}

// ---------------- weight prep: fp32 [K][N] -> bf16 [N][KP] (transposed, padded) ----
__global__ void prep_weights(const float* __restrict__ w0, const float* __restrict__ w1,
                             const float* __restrict__ w2, const float* __restrict__ r0,
                             const float* __restrict__ r1, const float* __restrict__ o0,
                             const float* __restrict__ o1, u16* __restrict__ wt)
{
  int idx = blockIdx.x * 256 + threadIdx.x;
  if (idx >= WTOT) return;
  const float* src; int K, Nsrc, KP, base;
  if (idx < WOFF_L1)      { src = w0; K = 36;  Nsrc = 256; KP = 64;  base = WOFF_L0; }
  else if (idx < WOFF_L2) { src = w1; K = 256; Nsrc = 256; KP = 256; base = WOFF_L1; }
  else if (idx < WOFF_R0) { src = w2; K = 256; Nsrc = 32;  KP = 256; base = WOFF_L2; }
  else if (idx < WOFF_R1) { src = r0; K = 32;  Nsrc = 256; KP = 32;  base = WOFF_R0; }
  else if (idx < WOFF_O0) { src = r1; K = 256; Nsrc = 32;  KP = 256; base = WOFF_R1; }
  else if (idx < WOFF_O1) { src = o0; K = 32;  Nsrc = 256; KP = 32;  base = WOFF_O0; }
  else                    { src = o1; K = 256; Nsrc = 2;   KP = 256; base = WOFF_O1; }
  int local = idx - base;
  int n = local / KP, k = local % KP;
  float v = (k < K && n < Nsrc) ? src[k * Nsrc + n] : 0.f;
  wt[idx] = f2bf(v);
}

// ---------------- bicubic helpers (torch aten A=-0.75, align_corners=False, zero pad)
__device__ __forceinline__ void cubw(float t, float w[4]) {
  const float A = -0.75f;
  float x = t + 1.f;
  w[0] = ((A * x - 5.f * A) * x + 8.f * A) * x - 4.f * A;
  w[1] = ((A + 2.f) * t - (A + 3.f)) * t * t + 1.f;
  float s = 1.f - t;
  w[2] = ((A + 2.f) * s - (A + 3.f)) * s * s + 1.f;
  w[3] = 1.f - w[0] - w[1] - w[2];
}

// 8-channel bicubic sample at (gx,gy); also accumulates interpolated LR coord field.
__device__ __forceinline__ void bicubic8(const float* __restrict__ bptr, float gx, float gy,
                                         float feat[8], float& qcy, float& qcx)
{
  float ix = ((gx + 1.f) * (float)WW - 1.f) * 0.5f;
  float iy = ((gy + 1.f) * (float)HH - 1.f) * 0.5f;
  float fx0 = floorf(ix), fy0 = floorf(iy);
  float tx = ix - fx0, ty = iy - fy0;
  float wx[4], wy[4];
  cubw(tx, wx); cubw(ty, wy);
  int ix0 = (int)fx0, iy0 = (int)fy0;
  #pragma unroll
  for (int c = 0; c < 8; c++) feat[c] = 0.f;
  qcy = 0.f; qcx = 0.f;
  #pragma unroll
  for (int i = 0; i < 4; i++) {
    int yi = iy0 - 1 + i;
    bool yok = (yi >= 0) && (yi < HH);
    int yc = min(max(yi, 0), HH - 1);
    float yv = -1.f + (2.f * yc + 1.f) * (1.f / HH);
    #pragma unroll
    for (int j = 0; j < 4; j++) {
      int xj = ix0 - 1 + j;
      bool ok = yok && (xj >= 0) && (xj < WW);
      if (!ok) continue;                       // zero-padding: tap contributes 0
      int xc = min(max(xj, 0), WW - 1);
      float wv = wy[i] * wx[j];
      const float* p = bptr + yc * WW + xc;
      #pragma unroll
      for (int c = 0; c < 8; c++) feat[c] = fmaf(wv, p[c * HWH], feat[c]);
      qcy = fmaf(wv, yv, qcy);
      qcx = fmaf(wv, (-1.f + (2.f * xc + 1.f) * (1.f / WW)), qcx);
    }
  }
}

// ---------------- wave-local MFMA layers -----------------------------------------
// A-frag: A[m=lane&15][k=quad*8+j]; B-frag: B[k=quad*8+j][n=lane&15] from Wt[n][KP];
// C/D: row=quad*4+r, col=lane&15. (verified layouts, learn_hip m89/m91/m120)
// Each wave processes ITS OWN 16 rows (rowb..rowb+15) and ALL 256 n, in 4 n-chunks.
// A-frags fully hoisted to registers before any epilogue write -> in-place safe.

template<int KP, int LSTR, bool RELU>
__device__ __forceinline__ void layer_n256w(const u16* lin, u16* lout,
                                            const u16* __restrict__ W,
                                            const float* __restrict__ bias,
                                            int rowb, int lm, int quad)
{
  constexpr int NK = KP / 32;
  bf16x8 a[NK];
  #pragma unroll
  for (int kk = 0; kk < NK; kk++)
    a[kk] = *(const bf16x8*)(lin + (rowb + lm) * LSTR + kk * 32 + quad * 8);
  #pragma unroll
  for (int nc = 0; nc < 4; nc++) {
    f32x4 acc[4];
    #pragma unroll
    for (int nt = 0; nt < 4; nt++) {
      float bv = bias[nc * 64 + nt * 16 + lm];
      acc[nt] = (f32x4){bv, bv, bv, bv};
    }
    #pragma unroll
    for (int kk = 0; kk < NK; kk++)
      #pragma unroll
      for (int nt = 0; nt < 4; nt++) {
        bf16x8 bf = *(const bf16x8*)(W + (nc * 64 + nt * 16 + lm) * KP + kk * 32 + quad * 8);
        acc[nt] = MFMA(a[kk], bf, acc[nt]);
      }
    #pragma unroll
    for (int nt = 0; nt < 4; nt++) {
      int col = nc * 64 + nt * 16 + lm;
      u16* base = lout + (rowb + quad * 4) * KPAD + col;
      #pragma unroll
      for (int r = 0; r < 4; r += 2) {
        float v0 = acc[nt][r], v1 = acc[nt][r + 1];
        if (RELU) { v0 = fmaxf(v0, 0.f); v1 = fmaxf(v1, 0.f); }
        uint32_t p = pkbf(v0, v1);
        base[r * KPAD]       = (u16)p;
        base[(r + 1) * KPAD] = (u16)(p >> 16);
      }
    }
  }
}

// N=32 head (K=256): wave computes both n-tiles for its own rows -> lout (PSTR).
__device__ __forceinline__ void layer_n32w(const u16* lin, u16* lout,
                                           const u16* __restrict__ W,
                                           const float* __restrict__ bias,
                                           int rowb, int lm, int quad)
{
  bf16x8 a[8];
  #pragma unroll
  for (int kk = 0; kk < 8; kk++)
    a[kk] = *(const bf16x8*)(lin + (rowb + lm) * KPAD + kk * 32 + quad * 8);
  f32x4 acc[2];
  #pragma unroll
  for (int nt = 0; nt < 2; nt++) {
    float bv = bias[nt * 16 + lm];
    acc[nt] = (f32x4){bv, bv, bv, bv};
  }
  #pragma unroll
  for (int kk = 0; kk < 8; kk++)
    #pragma unroll
    for (int nt = 0; nt < 2; nt++) {
      bf16x8 bf = *(const bf16x8*)(W + (nt * 16 + lm) * 256 + kk * 32 + quad * 8);
      acc[nt] = MFMA(a[kk], bf, acc[nt]);
    }
  #pragma unroll
  for (int nt = 0; nt < 2; nt++) {
    int col = nt * 16 + lm;
    #pragma unroll
    for (int r = 0; r < 4; r += 2) {
      float v0 = acc[nt][r], v1 = acc[nt][r + 1];
      uint32_t p = pkbf(v0, v1);
      lout[(rowb + quad * 4 + r) * PSTR + col]     = (u16)p;
      lout[(rowb + quad * 4 + r + 1) * PSTR + col] = (u16)(p >> 16);
    }
  }
}

// Offset head (K=256, N=2 padded to 16): wave-local, result -> offb (fp32).
__device__ __forceinline__ void layer_offw(const u16* act_, float* offb,
                                           const u16* __restrict__ W,
                                           const float* __restrict__ bias,
                                           int rowb, int lm, int quad)
{
  bf16x8 a[8];
  #pragma unroll
  for (int kk = 0; kk < 8; kk++)
    a[kk] = *(const bf16x8*)(act_ + (rowb + lm) * KPAD + kk * 32 + quad * 8);
  float bv = (lm < 2) ? bias[lm] : 0.f;
  f32x4 acc = {bv, bv, bv, bv};
  #pragma unroll
  for (int kk = 0; kk < 8; kk++) {
    bf16x8 bf = *(const bf16x8*)(W + lm * 256 + kk * 32 + quad * 8);
    acc = MFMA(a[kk], bf, acc);
  }
  if (lm < 2) {
    #pragma unroll
    for (int r = 0; r < 4; r++)
      offb[(rowb + quad * 4 + r) * 2 + lm] = acc[r];
  }
}

// ---------------- fused LIIF kernel: BARRIER-FREE (R6) ----------------------------
// M-split: wave w owns queries/rows [w*16, w*16+16). Lane = (quad: 8-channel group,
// lm: query). All LDS data flow is wave-private; ordering via LFENCE (lgkmcnt(0)),
// zero s_barrier. Each wave loads all N of each weight layer (4x loads, L1-amortized
// across the block's 4 near-lockstep waves).
__launch_bounds__(256, 3)
__global__ void liif_fused(const float* __restrict__ x, const u16* __restrict__ wt,
                           const float* __restrict__ b0, const float* __restrict__ b1,
                           const float* __restrict__ b2, const float* __restrict__ rb0,
                           const float* __restrict__ rb1, const float* __restrict__ ob0,
                           const float* __restrict__ ob1, float* __restrict__ out)
{
  __shared__ __align__(16) u16 act[MT * KPAD];    // 33792 B
  __shared__ __align__(16) u16 predb[MT * PSTR];  // 5120 B (pred, later routing)
  __shared__ float offb[MT * 2];                  // 512 B

  int t = threadIdx.x;
  int w = t >> 6;
  int lane = t & 63;
  int lm = lane & 15, quad = lane >> 4;
  int rowb = w * 16;
  int q = blockIdx.x * MT + rowb + lm;   // this lane's query
  int b = q >> 16;
  int qi = q & (QQ - 1);
  int oy = qi >> 8;
  int ox = qi & (WO - 1);

  float coordy = -1.f + (2.f * oy + 1.f) * (1.f / HO);
  float coordx = -1.f + (2.f * ox + 1.f) * (1.f / WO);
  float gy = fminf(fmaxf(coordy, -1.f + 1e-6f), 1.f - 1e-6f);
  float gx = fminf(fmaxf(coordx, -1.f + 1e-6f), 1.f - 1e-6f);

  const float* bptr = x + (b * CCH + quad * 8) * HWH;   // channel group = quad

  // ---- phase 0: bicubic q_feat + analytic q_coord -> own act rows
  {
    float feat[8], qcy, qcx;
    bicubic8(bptr, gx, gy, feat, qcy, qcx);
    union { uint32_t u[4]; bf16x8 v; } pk;
    #pragma unroll
    for (int c = 0; c < 4; c++) pk.u[c] = pkbf(feat[2 * c], feat[2 * c + 1]);
    *(bf16x8*)&act[(rowb + lm) * KPAD + quad * 8] = pk.v;
    if (quad == 0) {
      float rcy = (coordy - qcy) * (float)HH;
      float rcx = (coordx - qcx) * (float)WW;
      // faithful LIIF-quirk: cell[:,0] (query 0) *= 2/Ho ; cell[:,1] (query 1) *= 2/Wo
      float m = (qi == 0) ? (2.f / HO) : (qi == 1) ? (2.f / WO) : 1.f;
      uint32_t* r32 = (uint32_t*)&act[(rowb + lm) * KPAD + 32];
      r32[0] = pkbf(rcy, rcx);
      r32[1] = pkbf(m * (float)HH, m * (float)WW);
    } else if (quad == 1) {
      // zero K-pad cols 36..63 (row base 16B-aligned; +72 B -> 8B-aligned)
      uint64_t* z = (uint64_t*)&act[(rowb + lm) * KPAD + 36];
      #pragma unroll
      for (int k = 0; k < 7; k++) z[k] = 0ull;
    }
  }
  LFENCE();

  // ---- MLP chain, wave-local, in-place act buffer, no barriers
  layer_n256w<64, KPAD, true>(act, act, wt + WOFF_L0, b0, rowb, lm, quad);   // inp -> h0
  LFENCE();
  layer_n256w<256, KPAD, true>(act, act, wt + WOFF_L1, b1, rowb, lm, quad);  // h0 -> h1
  LFENCE();
  layer_n32w(act, predb, wt + WOFF_L2, b2, rowb, lm, quad);                  // h1 -> pred
  LFENCE();
  layer_n256w<32, PSTR, true>(predb, act, wt + WOFF_O0, ob0, rowb, lm, quad); // pred -> o0
  LFENCE();
  layer_offw(act, offb, wt + WOFF_O1, ob1, rowb, lm, quad);                  // o0 -> off
  LFENCE();
  layer_n256w<32, PSTR, true>(predb, act, wt + WOFF_R0, rb0, rowb, lm, quad); // pred -> r0
  LFENCE();
  layer_n32w(act, predb, wt + WOFF_R1, rb1, rowb, lm, quad);                 // r0 -> routing
  LFENCE();

  // ---- final: resample at offset coords, modulate by routing (bf16), store
  {
    float gx2 = gx + offb[(rowb + lm) * 2 + 0];
    float gy2 = gy + offb[(rowb + lm) * 2 + 1];
    float feat[8], d0, d1;
    bicubic8(bptr, gx2, gy2, feat, d0, d1);
    const u16* rp = &predb[(rowb + lm) * PSTR + quad * 8];
    float* op = out + (b * CCH + quad * 8) * (HO * WO) + oy * WO + ox;
    #pragma unroll
    for (int c = 0; c < 8; c++)
      op[c * (HO * WO)] = feat[c] * (1.f + bf2f(rp[c]));
  }
}

extern "C" void kernel_launch(void* const* d_in, const int* in_sizes, int n_in,
                              void* d_out, int out_size, void* d_ws, size_t ws_size,
                              hipStream_t stream)
{
  const float* x   = (const float*)d_in[0];
  const float* w0  = (const float*)d_in[1];
  const float* b0  = (const float*)d_in[2];
  const float* w1  = (const float*)d_in[3];
  const float* b1  = (const float*)d_in[4];
  const float* w2  = (const float*)d_in[5];
  const float* b2  = (const float*)d_in[6];
  const float* r0  = (const float*)d_in[7];
  const float* rb0 = (const float*)d_in[8];
  const float* r1  = (const float*)d_in[9];
  const float* rb1 = (const float*)d_in[10];
  const float* o0  = (const float*)d_in[11];
  const float* ob0 = (const float*)d_in[12];
  const float* o1  = (const float*)d_in[13];
  const float* ob1 = (const float*)d_in[14];
  u16* wt = (u16*)d_ws;
  float* out = (float*)d_out;

  prep_weights<<<(WTOT + 255) / 256, 256, 0, stream>>>(w0, w1, w2, r0, r1, o0, o1, wt);
  liif_fused<<<(BB * QQ) / MT, 256, 0, stream>>>(x, wt, b0, b1, b2, rb0, rb1, ob0, ob1, out);
}

// Round 7
// 252.269 us; speedup vs baseline: 2.0481x; 2.0481x over previous
//
#include <hip/hip_runtime.h>
#include <hip/hip_bf16.h>
#include <stdint.h>

// Problem constants (fixed shapes from setup_inputs)
#define BB 4
#define CCH 32
#define HH 128
#define WW 128
#define SCALE 2
#define HO 256
#define WO 256
#define QQ (HO*WO)          // 65536 queries per batch
#define HWH (HH*WW)         // 16384
#define MT 128              // queries per workgroup (R7: 8 m-tiles, 1:8 B-reuse)
#define KPAD 264            // act row stride (bf16): 256 + 8 pad
#define PSTR 40             // pred/routing row stride (bf16): 32 + 8 pad

// Transposed bf16 weight layout offsets in d_ws (elements), each [N][KP] row-major
#define WOFF_L0 0           // [256][64]   (K=36 zero-padded to 64)
#define WOFF_L1 16384       // [256][256]
#define WOFF_L2 81920       // [32][256]
#define WOFF_R0 90112       // [256][32]
#define WOFF_R1 98304       // [32][256]
#define WOFF_O0 106496      // [256][32]
#define WOFF_O1 114688      // [16][256]  (N=2 zero-padded to 16)
#define WTOT    118784

typedef unsigned short u16;
typedef __attribute__((ext_vector_type(8))) __bf16 bf16x8;
typedef __attribute__((ext_vector_type(4))) float f32x4;

__device__ __forceinline__ f32x4 MFMA(bf16x8 a, bf16x8 b, f32x4 c) {
  return __builtin_amdgcn_mfma_f32_16x16x32_bf16(a, b, c, 0, 0, 0);
}

// Software f32->bf16 RNE (cold paths only).
__device__ __forceinline__ u16 f2bf(float f) {
  union { float f; unsigned int u; } v; v.f = f;
  unsigned int u = v.u;
  u += 0x7fffu + ((u >> 16) & 1u);
  return (u16)(u >> 16);
}

// Packed f32x2 -> bf16x2 via hip_bf16 header (HW packed cvt, RNE). R4-proven.
__device__ __forceinline__ uint32_t pkbf(float a, float b) {
  union { __hip_bfloat162 h; uint32_t u; } cv;
  cv.h = __float22bfloat162_rn(make_float2(a, b));
  return cv.u;
}

__device__ __forceinline__ float bf2f(u16 u) {
  union { unsigned int u; float f; } v; v.u = ((unsigned int)u) << 16;
  return v.f;
}

// ---------------- weight prep: fp32 [K][N] -> bf16 [N][KP] (transposed, padded) ----
__global__ void prep_weights(const float* __restrict__ w0, const float* __restrict__ w1,
                             const float* __restrict__ w2, const float* __restrict__ r0,
                             const float* __restrict__ r1, const float* __restrict__ o0,
                             const float* __restrict__ o1, u16* __restrict__ wt)
{
  int idx = blockIdx.x * 256 + threadIdx.x;
  if (idx >= WTOT) return;
  const float* src; int K, Nsrc, KP, base;
  if (idx < WOFF_L1)      { src = w0; K = 36;  Nsrc = 256; KP = 64;  base = WOFF_L0; }
  else if (idx < WOFF_L2) { src = w1; K = 256; Nsrc = 256; KP = 256; base = WOFF_L1; }
  else if (idx < WOFF_R0) { src = w2; K = 256; Nsrc = 32;  KP = 256; base = WOFF_L2; }
  else if (idx < WOFF_R1) { src = r0; K = 32;  Nsrc = 256; KP = 32;  base = WOFF_R0; }
  else if (idx < WOFF_O0) { src = r1; K = 256; Nsrc = 32;  KP = 256; base = WOFF_R1; }
  else if (idx < WOFF_O1) { src = o0; K = 32;  Nsrc = 256; KP = 32;  base = WOFF_O0; }
  else                    { src = o1; K = 256; Nsrc = 2;   KP = 256; base = WOFF_O1; }
  int local = idx - base;
  int n = local / KP, k = local % KP;
  float v = (k < K && n < Nsrc) ? src[k * Nsrc + n] : 0.f;
  wt[idx] = f2bf(v);
}

// ---------------- bicubic helpers (torch aten A=-0.75, align_corners=False, zero pad)
__device__ __forceinline__ void cubw(float t, float w[4]) {
  const float A = -0.75f;
  float x = t + 1.f;
  w[0] = ((A * x - 5.f * A) * x + 8.f * A) * x - 4.f * A;
  w[1] = ((A + 2.f) * t - (A + 3.f)) * t * t + 1.f;
  float s = 1.f - t;
  w[2] = ((A + 2.f) * s - (A + 3.f)) * s * s + 1.f;
  w[3] = 1.f - w[0] - w[1] - w[2];
}

// 8-channel bicubic sample at (gx,gy); also accumulates interpolated LR coord field.
__device__ __forceinline__ void bicubic8(const float* __restrict__ bptr, float gx, float gy,
                                         float feat[8], float& qcy, float& qcx)
{
  float ix = ((gx + 1.f) * (float)WW - 1.f) * 0.5f;
  float iy = ((gy + 1.f) * (float)HH - 1.f) * 0.5f;
  float fx0 = floorf(ix), fy0 = floorf(iy);
  float tx = ix - fx0, ty = iy - fy0;
  float wx[4], wy[4];
  cubw(tx, wx); cubw(ty, wy);
  int ix0 = (int)fx0, iy0 = (int)fy0;
  #pragma unroll
  for (int c = 0; c < 8; c++) feat[c] = 0.f;
  qcy = 0.f; qcx = 0.f;
  #pragma unroll
  for (int i = 0; i < 4; i++) {
    int yi = iy0 - 1 + i;
    bool yok = (yi >= 0) && (yi < HH);
    int yc = min(max(yi, 0), HH - 1);
    float yv = -1.f + (2.f * yc + 1.f) * (1.f / HH);
    #pragma unroll
    for (int j = 0; j < 4; j++) {
      int xj = ix0 - 1 + j;
      bool ok = yok && (xj >= 0) && (xj < WW);
      if (!ok) continue;                       // zero-padding: tap contributes 0
      int xc = min(max(xj, 0), WW - 1);
      float wv = wy[i] * wx[j];
      const float* p = bptr + yc * WW + xc;
      #pragma unroll
      for (int c = 0; c < 8; c++) feat[c] = fmaf(wv, p[c * HWH], feat[c]);
      qcy = fmaf(wv, yv, qcy);
      qcx = fmaf(wv, (-1.f + (2.f * xc + 1.f) * (1.f / WW)), qcx);
    }
  }
}

// ---------------- MFMA layer routines (R5 N-split structure, 8 m-tiles) ----------
// A-frag: A[m=lane&15][k=quad*8+j]; B-frag: B[k=quad*8+j][n=lane&15] from Wt[n][KP];
// C/D: row=quad*4+r, col=lane&15. (verified layouts, learn_hip m89/m91/m120)

// N=256: wave w owns n in [w*64, w*64+64); loops all 8 m-tiles with B-frags held
// in registers across the K loop -> each B load feeds 8 MFMAs (1:8 reuse).
template<int KP, int LSTR, bool RELU, bool INPLACE>
__device__ __forceinline__ void layer_n256(const u16* lin, u16* lout,
                                           const u16* __restrict__ W,
                                           const float* __restrict__ bias, int w, int lane)
{
  int lm = lane & 15, quad = lane >> 4;
  int nbase = w * 64;
  f32x4 acc[8][4];     // 128 fp32 -> AGPRs
  #pragma unroll
  for (int nt = 0; nt < 4; nt++) {
    float bv = bias[nbase + nt * 16 + lm];
    f32x4 b4 = {bv, bv, bv, bv};
    #pragma unroll
    for (int mt = 0; mt < 8; mt++) acc[mt][nt] = b4;
  }
  #pragma unroll
  for (int kk = 0; kk < KP / 32; kk++) {
    bf16x8 bf[4];
    #pragma unroll
    for (int nt = 0; nt < 4; nt++)
      bf[nt] = *(const bf16x8*)(W + (nbase + nt * 16 + lm) * KP + kk * 32 + quad * 8);
    #pragma unroll
    for (int mt = 0; mt < 8; mt++) {
      bf16x8 af = *(const bf16x8*)(lin + (mt * 16 + lm) * LSTR + kk * 32 + quad * 8);
      #pragma unroll
      for (int nt = 0; nt < 4; nt++)
        acc[mt][nt] = MFMA(af, bf[nt], acc[mt][nt]);
    }
  }
  if (INPLACE) __syncthreads();   // all waves' reads of lin complete before overwrite
  #pragma unroll
  for (int mt = 0; mt < 8; mt++)
    #pragma unroll
    for (int nt = 0; nt < 4; nt++) {
      int col = nbase + nt * 16 + lm;
      u16* base = lout + (mt * 16 + quad * 4) * KPAD + col;
      #pragma unroll
      for (int r = 0; r < 4; r += 2) {
        float v0 = acc[mt][nt][r], v1 = acc[mt][nt][r + 1];
        if (RELU) { v0 = fmaxf(v0, 0.f); v1 = fmaxf(v1, 0.f); }
        uint32_t p = pkbf(v0, v1);
        base[r * KPAD]       = (u16)p;
        base[(r + 1) * KPAD] = (u16)(p >> 16);
      }
    }
}

// N=32 head (K=256): waves (0,1) take m-tiles 0..3, waves (2,3) take 4..7; nt=w&1.
// Output bf16 -> lout (PSTR layout, used for pred and routing).
__device__ __forceinline__ void layer_n32(const u16* lin, u16* lout,
                                          const u16* __restrict__ W,
                                          const float* __restrict__ bias, int w, int lane)
{
  int lm = lane & 15, quad = lane >> 4;
  int nt = w & 1, mtb = (w >> 1) * 4;
  float bv = bias[nt * 16 + lm];
  f32x4 acc[4];
  #pragma unroll
  for (int mi = 0; mi < 4; mi++) acc[mi] = (f32x4){bv, bv, bv, bv};
  #pragma unroll
  for (int kk = 0; kk < 8; kk++) {
    bf16x8 bf = *(const bf16x8*)(W + (nt * 16 + lm) * 256 + kk * 32 + quad * 8);
    #pragma unroll
    for (int mi = 0; mi < 4; mi++) {
      bf16x8 af = *(const bf16x8*)(lin + ((mtb + mi) * 16 + lm) * KPAD + kk * 32 + quad * 8);
      acc[mi] = MFMA(af, bf, acc[mi]);
    }
  }
  #pragma unroll
  for (int mi = 0; mi < 4; mi++) {
    int row0 = (mtb + mi) * 16 + quad * 4, col = nt * 16 + lm;
    #pragma unroll
    for (int r = 0; r < 4; r += 2) {
      float v0 = acc[mi][r], v1 = acc[mi][r + 1];
      uint32_t p = pkbf(v0, v1);
      lout[(row0 + r) * PSTR + col]     = (u16)p;
      lout[(row0 + r + 1) * PSTR + col] = (u16)(p >> 16);
    }
  }
}

// Offset head (K=256, N=2 padded to 16): wave w -> m-tiles {2w, 2w+1}.
__device__ __forceinline__ void layer_off(const u16* lin, float* offb,
                                          const u16* __restrict__ W,
                                          const float* __restrict__ bias, int w, int lane)
{
  int lm = lane & 15, quad = lane >> 4;
  int mtb = w * 2;
  float bv = (lm < 2) ? bias[lm] : 0.f;
  f32x4 acc[2];
  acc[0] = (f32x4){bv, bv, bv, bv};
  acc[1] = acc[0];
  #pragma unroll
  for (int kk = 0; kk < 8; kk++) {
    bf16x8 bf = *(const bf16x8*)(W + lm * 256 + kk * 32 + quad * 8);
    #pragma unroll
    for (int mi = 0; mi < 2; mi++) {
      bf16x8 af = *(const bf16x8*)(lin + ((mtb + mi) * 16 + lm) * KPAD + kk * 32 + quad * 8);
      acc[mi] = MFMA(af, bf, acc[mi]);
    }
  }
  if (lm < 2) {
    #pragma unroll
    for (int mi = 0; mi < 2; mi++)
      #pragma unroll
      for (int r = 0; r < 4; r++)
        offb[((mtb + mi) * 16 + quad * 4 + r) * 2 + lm] = acc[mi][r];
  }
}

// ---------------- fused LIIF kernel (R7: MT=128, 2 blocks/CU) ---------------------
__launch_bounds__(256, 2)
__global__ void liif_fused(const float* __restrict__ x, const u16* __restrict__ wt,
                           const float* __restrict__ b0, const float* __restrict__ b1,
                           const float* __restrict__ b2, const float* __restrict__ rb0,
                           const float* __restrict__ rb1, const float* __restrict__ ob0,
                           const float* __restrict__ ob1, float* __restrict__ out)
{
  __shared__ __align__(16) u16 act[MT * KPAD];    // 67584 B
  __shared__ __align__(16) u16 predb[MT * PSTR];  // 10240 B (pred, later routing)
  __shared__ float offb[MT * 2];                  // 1024 B
  __shared__ float gxy[MT * 2];                   // 1024 B   -> total 79872 B

  int t = threadIdx.x;
  int g = t >> 6;             // wave id == 8-channel group
  int lane = t & 63;
  int b = (blockIdx.x * MT) >> 16;                // batch (uniform per block)
  const float* bptr = x + (b * CCH + g * 8) * HWH;

  // ---- phase 0: bicubic q_feat + analytic q_coord; 2 queries per thread
  #pragma unroll
  for (int s = 0; s < 2; s++) {
    int ql = lane + s * 64;
    int qi = (blockIdx.x * MT + ql) & (QQ - 1);
    int oy = qi >> 8, ox = qi & (WO - 1);
    float coordy = -1.f + (2.f * oy + 1.f) * (1.f / HO);
    float coordx = -1.f + (2.f * ox + 1.f) * (1.f / WO);
    float gy = fminf(fmaxf(coordy, -1.f + 1e-6f), 1.f - 1e-6f);
    float gx = fminf(fmaxf(coordx, -1.f + 1e-6f), 1.f - 1e-6f);
    float feat[8], qcy, qcx;
    bicubic8(bptr, gx, gy, feat, qcy, qcx);
    union { uint32_t u[4]; bf16x8 v; } pk;
    #pragma unroll
    for (int c = 0; c < 4; c++) pk.u[c] = pkbf(feat[2 * c], feat[2 * c + 1]);
    *(bf16x8*)&act[ql * KPAD + g * 8] = pk.v;
    if (g == 0) {
      gxy[ql * 2 + 0] = gx;
      gxy[ql * 2 + 1] = gy;
      float rcy = (coordy - qcy) * (float)HH;
      float rcx = (coordx - qcx) * (float)WW;
      // faithful LIIF-quirk: cell[:,0] (query 0) *= 2/Ho ; cell[:,1] (query 1) *= 2/Wo
      float m = (qi == 0) ? (2.f / HO) : (qi == 1) ? (2.f / WO) : 1.f;
      act[ql * KPAD + 32] = f2bf(rcy);
      act[ql * KPAD + 33] = f2bf(rcx);
      act[ql * KPAD + 34] = f2bf(m * (float)HH);
      act[ql * KPAD + 35] = f2bf(m * (float)WW);
    } else if (g == 1) {
      // zero K-pad cols 36..63 (row base 16B-aligned; +72 B -> 8B-aligned)
      uint64_t* z = (uint64_t*)&act[ql * KPAD + 36];
      #pragma unroll
      for (int k = 0; k < 7; k++) z[k] = 0ull;
    }
  }
  __syncthreads();                                                        // B0

  // ---- MLP chain, single in-place activation buffer (R5-proven ordering)
  layer_n256<64, KPAD, true, true>(act, act, wt + WOFF_L0, b0, g, lane);   // inp -> h0
  __syncthreads();                                                         // B1
  layer_n256<256, KPAD, true, true>(act, act, wt + WOFF_L1, b1, g, lane);  // h0 -> h1
  __syncthreads();                                                         // B2
  layer_n32(act, predb, wt + WOFF_L2, b2, g, lane);                        // h1 -> pred
  __syncthreads();                                                         // B3
  layer_n256<32, PSTR, true, false>(predb, act, wt + WOFF_O0, ob0, g, lane); // pred -> o0
  __syncthreads();                                                         // B4
  layer_off(act, offb, wt + WOFF_O1, ob1, g, lane);                        // o0 -> off
  __syncthreads();                                                         // B5
  layer_n256<32, PSTR, true, false>(predb, act, wt + WOFF_R0, rb0, g, lane); // pred -> r0
  __syncthreads();                                                         // B6
  layer_n32(act, predb, wt + WOFF_R1, rb1, g, lane);                       // r0 -> routing
  __syncthreads();                                                         // B7

  // ---- final: resample at offset coords, modulate by routing (bf16), store
  #pragma unroll
  for (int s = 0; s < 2; s++) {
    int ql = lane + s * 64;
    int qi = (blockIdx.x * MT + ql) & (QQ - 1);
    int oy = qi >> 8, ox = qi & (WO - 1);
    float gx2 = gxy[ql * 2 + 0] + offb[ql * 2 + 0];
    float gy2 = gxy[ql * 2 + 1] + offb[ql * 2 + 1];
    float feat[8], d0, d1;
    bicubic8(bptr, gx2, gy2, feat, d0, d1);
    const u16* rp = &predb[ql * PSTR + g * 8];
    float* op = out + (b * CCH + g * 8) * (HO * WO) + oy * WO + ox;
    #pragma unroll
    for (int c = 0; c < 8; c++)
      op[c * (HO * WO)] = feat[c] * (1.f + bf2f(rp[c]));
  }
}

extern "C" void kernel_launch(void* const* d_in, const int* in_sizes, int n_in,
                              void* d_out, int out_size, void* d_ws, size_t ws_size,
                              hipStream_t stream)
{
  const float* x   = (const float*)d_in[0];
  const float* w0  = (const float*)d_in[1];
  const float* b0  = (const float*)d_in[2];
  const float* w1  = (const float*)d_in[3];
  const float* b1  = (const float*)d_in[4];
  const float* w2  = (const float*)d_in[5];
  const float* b2  = (const float*)d_in[6];
  const float* r0  = (const float*)d_in[7];
  const float* rb0 = (const float*)d_in[8];
  const float* r1  = (const float*)d_in[9];
  const float* rb1 = (const float*)d_in[10];
  const float* o0  = (const float*)d_in[11];
  const float* ob0 = (const float*)d_in[12];
  const float* o1  = (const float*)d_in[13];
  const float* ob1 = (const float*)d_in[14];
  u16* wt = (u16*)d_ws;
  float* out = (float*)d_out;

  prep_weights<<<(WTOT + 255) / 256, 256, 0, stream>>>(w0, w1, w2, r0, r1, o0, o1, wt);
  liif_fused<<<(BB * QQ) / MT, 256, 0, stream>>>(x, wt, b0, b1, b2, rb0, rb1, ob0, ob1, out);
}

// Round 8
// 221.164 us; speedup vs baseline: 2.3362x; 1.1406x over previous
//
#include <hip/hip_runtime.h>
#include <hip/hip_bf16.h>
#include <stdint.h>

// Problem constants (fixed shapes from setup_inputs)
#define BB 4
#define CCH 32
#define HH 128
#define WW 128
#define SCALE 2
#define HO 256
#define WO 256
#define QQ (HO*WO)          // 65536 queries per batch
#define HWH (HH*WW)         // 16384
#define MT 128              // queries per workgroup (8 m-tiles, 1:8 B-reuse)
#define KPAD 264            // act row stride (bf16): 256 + 8 pad
#define PSTR 40             // pred/routing row stride (bf16): 32 + 8 pad

// Transposed bf16 weight layout offsets in d_ws (elements), each [N][KP] row-major
#define WOFF_L0 0           // [256][64]   (K=36 zero-padded to 64)
#define WOFF_L1 16384       // [256][256]
#define WOFF_L2 81920       // [32][256]
#define WOFF_R0 90112       // [256][32]
#define WOFF_R1 98304       // [32][256]
#define WOFF_O0 106496      // [256][32]
#define WOFF_O1 114688      // [16][256]  (N=2 zero-padded to 16)
#define WTOT    118784

typedef unsigned short u16;
typedef __attribute__((ext_vector_type(8))) __bf16 bf16x8;
typedef __attribute__((ext_vector_type(4))) float f32x4;

__device__ __forceinline__ f32x4 MFMA(bf16x8 a, bf16x8 b, f32x4 c) {
  return __builtin_amdgcn_mfma_f32_16x16x32_bf16(a, b, c, 0, 0, 0);
}

// Software f32->bf16 RNE (cold paths only).
__device__ __forceinline__ u16 f2bf(float f) {
  union { float f; unsigned int u; } v; v.f = f;
  unsigned int u = v.u;
  u += 0x7fffu + ((u >> 16) & 1u);
  return (u16)(u >> 16);
}

// Packed f32x2 -> bf16x2 via hip_bf16 header (HW packed cvt, RNE). R4-proven.
__device__ __forceinline__ uint32_t pkbf(float a, float b) {
  union { __hip_bfloat162 h; uint32_t u; } cv;
  cv.h = __float22bfloat162_rn(make_float2(a, b));
  return cv.u;
}

__device__ __forceinline__ float bf2f(u16 u) {
  union { unsigned int u; float f; } v; v.u = ((unsigned int)u) << 16;
  return v.f;
}

// ---------------- weight prep: fp32 [K][N] -> bf16 [N][KP] (transposed, padded) ----
__global__ void prep_weights(const float* __restrict__ w0, const float* __restrict__ w1,
                             const float* __restrict__ w2, const float* __restrict__ r0,
                             const float* __restrict__ r1, const float* __restrict__ o0,
                             const float* __restrict__ o1, u16* __restrict__ wt)
{
  int idx = blockIdx.x * 256 + threadIdx.x;
  if (idx >= WTOT) return;
  const float* src; int K, Nsrc, KP, base;
  if (idx < WOFF_L1)      { src = w0; K = 36;  Nsrc = 256; KP = 64;  base = WOFF_L0; }
  else if (idx < WOFF_L2) { src = w1; K = 256; Nsrc = 256; KP = 256; base = WOFF_L1; }
  else if (idx < WOFF_R0) { src = w2; K = 256; Nsrc = 32;  KP = 256; base = WOFF_L2; }
  else if (idx < WOFF_R1) { src = r0; K = 32;  Nsrc = 256; KP = 32;  base = WOFF_R0; }
  else if (idx < WOFF_O0) { src = r1; K = 256; Nsrc = 32;  KP = 256; base = WOFF_R1; }
  else if (idx < WOFF_O1) { src = o0; K = 32;  Nsrc = 256; KP = 32;  base = WOFF_O0; }
  else                    { src = o1; K = 256; Nsrc = 2;   KP = 256; base = WOFF_O1; }
  int local = idx - base;
  int n = local / KP, k = local % KP;
  float v = (k < K && n < Nsrc) ? src[k * Nsrc + n] : 0.f;
  wt[idx] = f2bf(v);
}

// ---------------- bicubic (torch aten A=-0.75, align_corners=False, zero pad) -----
__device__ __forceinline__ void cubw(float t, float w[4]) {
  const float A = -0.75f;
  float x = t + 1.f;
  w[0] = ((A * x - 5.f * A) * x + 8.f * A) * x - 4.f * A;
  w[1] = ((A + 2.f) * t - (A + 3.f)) * t * t + 1.f;
  float s = 1.f - t;
  w[2] = ((A + 2.f) * s - (A + 3.f)) * s * s + 1.f;
  w[3] = 1.f - w[0] - w[1] - w[2];
}

// Row-vectorized 8-channel bicubic: one dwordx4 per (row, channel) from a clamped
// 4-wide window; x-weights shift-masked onto the window (OOB tap -> weight 0,
// fma(0,p,acc)==acc keeps results bitwise-identical to the tap-masked version).
// Also returns the interpolated LR coord field (qcy,qcx).
__device__ __forceinline__ void bicubic8_rows(const float* __restrict__ bptr,
                                              int ix0, int iy0,
                                              const float wx[4], const float wy[4],
                                              float feat[8], float& qcy, float& qcx)
{
  int bx = min(max(ix0 - 1, 0), WW - 4);
  int d = bx - (ix0 - 1);               // loaded i holds tap j = i + d
  float wl[4];
  #pragma unroll
  for (int i = 0; i < 4; i++) {
    int j = i + d;
    float w = 0.f;
    w = (j == 0) ? wx[0] : w;
    w = (j == 1) ? wx[1] : w;
    w = (j == 2) ? wx[2] : w;
    w = (j == 3) ? wx[3] : w;
    wl[i] = w;
  }
  float wyl[4]; int yrow[4];
  #pragma unroll
  for (int i = 0; i < 4; i++) {
    int y = iy0 - 1 + i;
    wyl[i] = (y >= 0 && y < HH) ? wy[i] : 0.f;
    yrow[i] = min(max(y, 0), HH - 1);
  }
  float w16[4][4];
  #pragma unroll
  for (int i = 0; i < 4; i++)
    #pragma unroll
    for (int j = 0; j < 4; j++) w16[i][j] = wyl[i] * wl[j];

  #pragma unroll
  for (int c = 0; c < 8; c++) feat[c] = 0.f;
  float ydot = 0.f, wysum = 0.f;
  #pragma unroll
  for (int i = 0; i < 4; i++) {
    const float* rp = bptr + yrow[i] * WW + bx;
    #pragma unroll
    for (int c = 0; c < 8; c++) {
      float4 p;
      __builtin_memcpy(&p, rp + c * HWH, 16);   // align-4 dwordx4
      feat[c] = fmaf(w16[i][0], p.x, feat[c]);
      feat[c] = fmaf(w16[i][1], p.y, feat[c]);
      feat[c] = fmaf(w16[i][2], p.z, feat[c]);
      feat[c] = fmaf(w16[i][3], p.w, feat[c]);
    }
    float yv = -1.f + (2.f * yrow[i] + 1.f) * (1.f / HH);
    ydot = fmaf(wyl[i], yv, ydot);
    wysum += wyl[i];
  }
  float wlsum = (wl[0] + wl[1]) + (wl[2] + wl[3]);
  float xb = -1.f + (2.f * bx + 1.f) * (1.f / WW);
  float xdot = wl[0] * xb;
  xdot = fmaf(wl[1], xb + 2.f / WW, xdot);
  xdot = fmaf(wl[2], xb + 4.f / WW, xdot);
  xdot = fmaf(wl[3], xb + 6.f / WW, xdot);
  qcy = wlsum * ydot;
  qcx = wysum * xdot;
}

// Arbitrary-coordinate wrapper (final offset sample).
__device__ __forceinline__ void bicubic8_any(const float* __restrict__ bptr, float gx, float gy,
                                             float feat[8], float& qcy, float& qcx)
{
  float ix = ((gx + 1.f) * (float)WW - 1.f) * 0.5f;
  float iy = ((gy + 1.f) * (float)HH - 1.f) * 0.5f;
  float fx0 = floorf(ix), fy0 = floorf(iy);
  float wx[4], wy[4];
  cubw(ix - fx0, wx);
  cubw(iy - fy0, wy);
  bicubic8_rows(bptr, (int)fx0, (int)fy0, wx, wy, feat, qcy, qcx);
}

// scale=2 lattice (phase 0): ix=(2o-1)/4 exactly -> t in {0.25,0.75} exactly;
// weights are two constant sets (exact cubw(0.25) values), i0=(o-1)>>1.
__device__ __forceinline__ void latt_w(int o, float w[4], int& i0) {
  const float W0 = -0.10546875f, W1 = 0.87890625f, W2 = 0.26171875f, W3 = -0.03515625f;
  bool odd = (o & 1);                   // odd -> t=0.25 ; even -> t=0.75 (reversed)
  w[0] = odd ? W0 : W3;
  w[1] = odd ? W1 : W2;
  w[2] = odd ? W2 : W1;
  w[3] = odd ? W3 : W0;
  i0 = (o - 1) >> 1;
}

// ---------------- MFMA layer routines (R7 N-split, 8 m-tiles, unchanged) ---------
// A-frag: A[m=lane&15][k=quad*8+j]; B-frag: B[k=quad*8+j][n=lane&15] from Wt[n][KP];
// C/D: row=quad*4+r, col=lane&15. (verified layouts, learn_hip m89/m91/m120)

template<int KP, int LSTR, bool RELU, bool INPLACE>
__device__ __forceinline__ void layer_n256(const u16* lin, u16* lout,
                                           const u16* __restrict__ W,
                                           const float* __restrict__ bias, int w, int lane)
{
  int lm = lane & 15, quad = lane >> 4;
  int nbase = w * 64;
  f32x4 acc[8][4];     // 128 fp32 -> AGPRs
  #pragma unroll
  for (int nt = 0; nt < 4; nt++) {
    float bv = bias[nbase + nt * 16 + lm];
    f32x4 b4 = {bv, bv, bv, bv};
    #pragma unroll
    for (int mt = 0; mt < 8; mt++) acc[mt][nt] = b4;
  }
  #pragma unroll
  for (int kk = 0; kk < KP / 32; kk++) {
    bf16x8 bf[4];
    #pragma unroll
    for (int nt = 0; nt < 4; nt++)
      bf[nt] = *(const bf16x8*)(W + (nbase + nt * 16 + lm) * KP + kk * 32 + quad * 8);
    #pragma unroll
    for (int mt = 0; mt < 8; mt++) {
      bf16x8 af = *(const bf16x8*)(lin + (mt * 16 + lm) * LSTR + kk * 32 + quad * 8);
      #pragma unroll
      for (int nt = 0; nt < 4; nt++)
        acc[mt][nt] = MFMA(af, bf[nt], acc[mt][nt]);
    }
  }
  if (INPLACE) __syncthreads();   // all waves' reads of lin complete before overwrite
  #pragma unroll
  for (int mt = 0; mt < 8; mt++)
    #pragma unroll
    for (int nt = 0; nt < 4; nt++) {
      int col = nbase + nt * 16 + lm;
      u16* base = lout + (mt * 16 + quad * 4) * KPAD + col;
      #pragma unroll
      for (int r = 0; r < 4; r += 2) {
        float v0 = acc[mt][nt][r], v1 = acc[mt][nt][r + 1];
        if (RELU) { v0 = fmaxf(v0, 0.f); v1 = fmaxf(v1, 0.f); }
        uint32_t p = pkbf(v0, v1);
        base[r * KPAD]       = (u16)p;
        base[(r + 1) * KPAD] = (u16)(p >> 16);
      }
    }
}

// N=32 head (K=256): waves (0,1) take m-tiles 0..3, waves (2,3) take 4..7; nt=w&1.
__device__ __forceinline__ void layer_n32(const u16* lin, u16* lout,
                                          const u16* __restrict__ W,
                                          const float* __restrict__ bias, int w, int lane)
{
  int lm = lane & 15, quad = lane >> 4;
  int nt = w & 1, mtb = (w >> 1) * 4;
  float bv = bias[nt * 16 + lm];
  f32x4 acc[4];
  #pragma unroll
  for (int mi = 0; mi < 4; mi++) acc[mi] = (f32x4){bv, bv, bv, bv};
  #pragma unroll
  for (int kk = 0; kk < 8; kk++) {
    bf16x8 bf = *(const bf16x8*)(W + (nt * 16 + lm) * 256 + kk * 32 + quad * 8);
    #pragma unroll
    for (int mi = 0; mi < 4; mi++) {
      bf16x8 af = *(const bf16x8*)(lin + ((mtb + mi) * 16 + lm) * KPAD + kk * 32 + quad * 8);
      acc[mi] = MFMA(af, bf, acc[mi]);
    }
  }
  #pragma unroll
  for (int mi = 0; mi < 4; mi++) {
    int row0 = (mtb + mi) * 16 + quad * 4, col = nt * 16 + lm;
    #pragma unroll
    for (int r = 0; r < 4; r += 2) {
      float v0 = acc[mi][r], v1 = acc[mi][r + 1];
      uint32_t p = pkbf(v0, v1);
      lout[(row0 + r) * PSTR + col]     = (u16)p;
      lout[(row0 + r + 1) * PSTR + col] = (u16)(p >> 16);
    }
  }
}

// Offset head (K=256, N=2 padded to 16): wave w -> m-tiles {2w, 2w+1}.
__device__ __forceinline__ void layer_off(const u16* lin, float* offb,
                                          const u16* __restrict__ W,
                                          const float* __restrict__ bias, int w, int lane)
{
  int lm = lane & 15, quad = lane >> 4;
  int mtb = w * 2;
  float bv = (lm < 2) ? bias[lm] : 0.f;
  f32x4 acc[2];
  acc[0] = (f32x4){bv, bv, bv, bv};
  acc[1] = acc[0];
  #pragma unroll
  for (int kk = 0; kk < 8; kk++) {
    bf16x8 bf = *(const bf16x8*)(W + lm * 256 + kk * 32 + quad * 8);
    #pragma unroll
    for (int mi = 0; mi < 2; mi++) {
      bf16x8 af = *(const bf16x8*)(lin + ((mtb + mi) * 16 + lm) * KPAD + kk * 32 + quad * 8);
      acc[mi] = MFMA(af, bf, acc[mi]);
    }
  }
  if (lm < 2) {
    #pragma unroll
    for (int mi = 0; mi < 2; mi++)
      #pragma unroll
      for (int r = 0; r < 4; r++)
        offb[((mtb + mi) * 16 + quad * 4 + r) * 2 + lm] = acc[mi][r];
  }
}

// ---------------- fused LIIF kernel (MT=128, 2 blocks/CU) -------------------------
__launch_bounds__(256, 2)
__global__ void liif_fused(const float* __restrict__ x, const u16* __restrict__ wt,
                           const float* __restrict__ b0, const float* __restrict__ b1,
                           const float* __restrict__ b2, const float* __restrict__ rb0,
                           const float* __restrict__ rb1, const float* __restrict__ ob0,
                           const float* __restrict__ ob1, float* __restrict__ out)
{
  __shared__ __align__(16) u16 act[MT * KPAD];    // 67584 B
  __shared__ __align__(16) u16 predb[MT * PSTR];  // 10240 B (pred, later routing)
  __shared__ float offb[MT * 2];                  // 1024 B
  __shared__ float gxy[MT * 2];                   // 1024 B   -> total 79872 B

  int t = threadIdx.x;
  int g = t >> 6;             // wave id == 8-channel group
  int lane = t & 63;
  int b = (blockIdx.x * MT) >> 16;                // batch (uniform per block)
  const float* bptr = x + (b * CCH + g * 8) * HWH;

  // ---- phase 0: lattice bicubic q_feat + analytic q_coord; 2 queries per thread
  #pragma unroll
  for (int s = 0; s < 2; s++) {
    int ql = lane + s * 64;
    int qi = (blockIdx.x * MT + ql) & (QQ - 1);
    int oy = qi >> 8, ox = qi & (WO - 1);
    float coordy = -1.f + (2.f * oy + 1.f) * (1.f / HO);
    float coordx = -1.f + (2.f * ox + 1.f) * (1.f / WO);
    float gy = fminf(fmaxf(coordy, -1.f + 1e-6f), 1.f - 1e-6f);
    float gx = fminf(fmaxf(coordx, -1.f + 1e-6f), 1.f - 1e-6f);
    float wx[4], wy[4]; int ix0, iy0;
    latt_w(ox, wx, ix0);
    latt_w(oy, wy, iy0);
    float feat[8], qcy, qcx;
    bicubic8_rows(bptr, ix0, iy0, wx, wy, feat, qcy, qcx);
    union { uint32_t u[4]; bf16x8 v; } pk;
    #pragma unroll
    for (int c = 0; c < 4; c++) pk.u[c] = pkbf(feat[2 * c], feat[2 * c + 1]);
    *(bf16x8*)&act[ql * KPAD + g * 8] = pk.v;
    if (g == 0) {
      gxy[ql * 2 + 0] = gx;
      gxy[ql * 2 + 1] = gy;
      float rcy = (coordy - qcy) * (float)HH;
      float rcx = (coordx - qcx) * (float)WW;
      // faithful LIIF-quirk: cell[:,0] (query 0) *= 2/Ho ; cell[:,1] (query 1) *= 2/Wo
      float m = (qi == 0) ? (2.f / HO) : (qi == 1) ? (2.f / WO) : 1.f;
      act[ql * KPAD + 32] = f2bf(rcy);
      act[ql * KPAD + 33] = f2bf(rcx);
      act[ql * KPAD + 34] = f2bf(m * (float)HH);
      act[ql * KPAD + 35] = f2bf(m * (float)WW);
    } else if (g == 1) {
      // zero K-pad cols 36..63 (row base 16B-aligned; +72 B -> 8B-aligned)
      uint64_t* z = (uint64_t*)&act[ql * KPAD + 36];
      #pragma unroll
      for (int k = 0; k < 7; k++) z[k] = 0ull;
    }
  }
  __syncthreads();                                                        // B0

  // ---- MLP chain, single in-place activation buffer (R5/R7-proven ordering)
  layer_n256<64, KPAD, true, true>(act, act, wt + WOFF_L0, b0, g, lane);   // inp -> h0
  __syncthreads();                                                         // B1
  layer_n256<256, KPAD, true, true>(act, act, wt + WOFF_L1, b1, g, lane);  // h0 -> h1
  __syncthreads();                                                         // B2
  layer_n32(act, predb, wt + WOFF_L2, b2, g, lane);                        // h1 -> pred
  __syncthreads();                                                         // B3
  layer_n256<32, PSTR, true, false>(predb, act, wt + WOFF_O0, ob0, g, lane); // pred -> o0
  __syncthreads();                                                         // B4
  layer_off(act, offb, wt + WOFF_O1, ob1, g, lane);                        // o0 -> off
  __syncthreads();                                                         // B5
  layer_n256<32, PSTR, true, false>(predb, act, wt + WOFF_R0, rb0, g, lane); // pred -> r0
  __syncthreads();                                                         // B6
  layer_n32(act, predb, wt + WOFF_R1, rb1, g, lane);                       // r0 -> routing
  __syncthreads();                                                         // B7

  // ---- final: resample at offset coords, modulate by routing (bf16), store
  #pragma unroll
  for (int s = 0; s < 2; s++) {
    int ql = lane + s * 64;
    int qi = (blockIdx.x * MT + ql) & (QQ - 1);
    int oy = qi >> 8, ox = qi & (WO - 1);
    float gx2 = gxy[ql * 2 + 0] + offb[ql * 2 + 0];
    float gy2 = gxy[ql * 2 + 1] + offb[ql * 2 + 1];
    float feat[8], d0, d1;
    bicubic8_any(bptr, gx2, gy2, feat, d0, d1);
    const u16* rp = &predb[ql * PSTR + g * 8];
    float* op = out + (b * CCH + g * 8) * (HO * WO) + oy * WO + ox;
    #pragma unroll
    for (int c = 0; c < 8; c++)
      op[c * (HO * WO)] = feat[c] * (1.f + bf2f(rp[c]));
  }
}

extern "C" void kernel_launch(void* const* d_in, const int* in_sizes, int n_in,
                              void* d_out, int out_size, void* d_ws, size_t ws_size,
                              hipStream_t stream)
{
  const float* x   = (const float*)d_in[0];
  const float* w0  = (const float*)d_in[1];
  const float* b0  = (const float*)d_in[2];
  const float* w1  = (const float*)d_in[3];
  const float* b1  = (const float*)d_in[4];
  const float* w2  = (const float*)d_in[5];
  const float* b2  = (const float*)d_in[6];
  const float* r0  = (const float*)d_in[7];
  const float* rb0 = (const float*)d_in[8];
  const float* r1  = (const float*)d_in[9];
  const float* rb1 = (const float*)d_in[10];
  const float* o0  = (const float*)d_in[11];
  const float* ob0 = (const float*)d_in[12];
  const float* o1  = (const float*)d_in[13];
  const float* ob1 = (const float*)d_in[14];
  u16* wt = (u16*)d_ws;
  float* out = (float*)d_out;

  prep_weights<<<(WTOT + 255) / 256, 256, 0, stream>>>(w0, w1, w2, r0, r1, o0, o1, wt);
  liif_fused<<<(BB * QQ) / MT, 256, 0, stream>>>(x, wt, b0, b1, b2, rb0, rb1, ob0, ob1, out);
}